// Round 14
// baseline (465.312 us; speedup 1.0000x reference)
//
#include <hip/hip_runtime.h>
#include <hip/hip_bf16.h>
#include <stdint.h>

#define DIMSZ 1024
#define BN_TOT 8192   // B*N
#define NSEQ 2048
#define NHEADS 16
#define DHEAD 64

typedef __attribute__((ext_vector_type(8))) __bf16 bf16x8;
typedef __attribute__((ext_vector_type(4))) float f32x4;

__device__ __forceinline__ float bf2f(ushort u) {
  return __uint_as_float(((uint32_t)u) << 16);
}
__device__ __forceinline__ ushort f2bf(float f) {
  uint32_t u = __float_as_uint(f);
  u += 0x7FFFu + ((u >> 16) & 1u);   // round-to-nearest-even
  return (ushort)(u >> 16);
}
// pack two f32 -> two bf16 in one u32 (RNE), lo = first operand
__device__ __forceinline__ uint32_t cvt_pk_bf16(float lo, float hi) {
  uint32_t r;
  asm("v_cvt_pk_bf16_f32 %0, %1, %2" : "=v"(r) : "v"(lo), "v"(hi));
  return r;
}
// async global -> LDS, 16B per lane. LDS dest must be wave-uniform base.
__device__ __forceinline__ void gl_lds16(const ushort* g, ushort* l) {
  __builtin_amdgcn_global_load_lds(
      (const __attribute__((address_space(1))) void*)g,
      (__attribute__((address_space(3))) void*)l, 16, 0, 0);
}

// ---------------- LayerNorm: x[8192][1024] f32 -> xn bf16 ----------------
__global__ __launch_bounds__(256) void layernorm_k(
    const float* __restrict__ x, const float* __restrict__ gamma,
    const float* __restrict__ beta, ushort* __restrict__ xn) {
  const int row = blockIdx.x;
  const int tid = threadIdx.x;
  const float* xr = x + (size_t)row * DIMSZ;
  float4 v = *(const float4*)(xr + tid * 4);
  float s = v.x + v.y + v.z + v.w;
  float ss = v.x * v.x + v.y * v.y + v.z * v.z + v.w * v.w;
#pragma unroll
  for (int o = 1; o < 64; o <<= 1) { s += __shfl_xor(s, o); ss += __shfl_xor(ss, o); }
  __shared__ float red[2][4];
  const int wid = tid >> 6;
  if ((tid & 63) == 0) { red[0][wid] = s; red[1][wid] = ss; }
  __syncthreads();
  s = red[0][0] + red[0][1] + red[0][2] + red[0][3];
  ss = red[1][0] + red[1][1] + red[1][2] + red[1][3];
  const float mu = s * (1.0f / DIMSZ);
  const float var = ss * (1.0f / DIMSZ) - mu * mu;
  const float rstd = rsqrtf(var + 1e-5f);
  float4 g = *(const float4*)(gamma + tid * 4);
  float4 bb = *(const float4*)(beta + tid * 4);
  ushort4 o4;
  o4.x = f2bf((v.x - mu) * rstd * g.x + bb.x);
  o4.y = f2bf((v.y - mu) * rstd * g.y + bb.y);
  o4.z = f2bf((v.z - mu) * rstd * g.z + bb.z);
  o4.w = f2bf((v.w - mu) * rstd * g.w + bb.w);
  *(ushort4*)(xn + (size_t)row * DIMSZ + tid * 4) = o4;
}

// -- in-place row L2-normalize + exact GELU on bf16 buffer, ssq precomputed --
__global__ __launch_bounds__(256) void normgelu_bf_k(
    ushort* __restrict__ buf, const float* __restrict__ ssq) {
  const size_t row = (size_t)blockIdx.y * BN_TOT + blockIdx.x;
  ushort* p = buf + row * DIMSZ + threadIdx.x * 4;
  const float inv = 1.0f / fmaxf(sqrtf(ssq[row]), 1e-12f);
  ushort4 v = *(const ushort4*)p;
  ushort4 o4;
  float x0;
  x0 = bf2f(v.x) * inv; o4.x = f2bf(0.5f * x0 * (1.0f + erff(x0 * 0.70710678118654752f)));
  x0 = bf2f(v.y) * inv; o4.y = f2bf(0.5f * x0 * (1.0f + erff(x0 * 0.70710678118654752f)));
  x0 = bf2f(v.z) * inv; o4.z = f2bf(0.5f * x0 * (1.0f + erff(x0 * 0.70710678118654752f)));
  x0 = bf2f(v.w) * inv; o4.w = f2bf(0.5f * x0 * (1.0f + erff(x0 * 0.70710678118654752f)));
  *(ushort4*)p = o4;
}

// ----------- f32 -> bf16 copy, 4 weight matrices batched on z -----------
__global__ void cvt4_k(const float* __restrict__ s0, const float* __restrict__ s1,
                       const float* __restrict__ s2, const float* __restrict__ s3,
                       ushort* __restrict__ out) {
  const int z = blockIdx.z;
  const float* in = (z == 0) ? s0 : (z == 1) ? s1 : (z == 2) ? s2 : s3;
  const int i = (blockIdx.x * 256 + threadIdx.x) * 4;
  float4 v = *(const float4*)(in + i);
  ushort4 o;
  o.x = f2bf(v.x); o.y = f2bf(v.y); o.z = f2bf(v.z); o.w = f2bf(v.w);
  *(ushort4*)(out + (size_t)z * DIMSZ * DIMSZ + i) = o;
}

// -- transpose+convert val [P][E] f32 -> valT [E][P] bf16, 4 matrices on z --
__global__ __launch_bounds__(256) void transpose_cvt4_k(
    const float* __restrict__ s0, const float* __restrict__ s1,
    const float* __restrict__ s2, const float* __restrict__ s3,
    ushort* __restrict__ out) {
  __shared__ float t[32][33];
  const int z = blockIdx.z;
  const float* in = (z == 0) ? s0 : (z == 1) ? s1 : (z == 2) ? s2 : s3;
  ushort* dst = out + (size_t)z * DIMSZ * DIMSZ;
  const int tx = threadIdx.x & 31;
  const int ty = threadIdx.x >> 5;  // 0..7
  const int bx = blockIdx.x * 32;   // col block of in (E)
  const int by = blockIdx.y * 32;   // row block of in (P)
#pragma unroll
  for (int i = 0; i < 32; i += 8)
    t[ty + i][tx] = in[(size_t)(by + ty + i) * DIMSZ + bx + tx];
  __syncthreads();
#pragma unroll
  for (int i = 0; i < 32; i += 8)
    dst[(size_t)(bx + ty + i) * DIMSZ + by + tx] = f2bf(t[tx][ty + i]);
}

// ---- V transpose (bf16): vb[8192][1024] -> vt[64 bh][64 d][2048 n] ----
__global__ __launch_bounds__(256) void transpose_v_k(
    const ushort* __restrict__ vb, ushort* __restrict__ vt) {
  __shared__ ushort t[32][33];
  const int bh = blockIdx.x;        // 0..63
  const int nt = blockIdx.y;        // 0..63 (n tile)
  const int dt = blockIdx.z;        // 0..1  (d tile)
  const int b = bh >> 4, h = bh & 15;
  const int tx = threadIdx.x & 31;
  const int ty = threadIdx.x >> 5;  // 0..7
  const size_t inbase = ((size_t)b * NSEQ + nt * 32) * DIMSZ + h * DHEAD + dt * 32;
#pragma unroll
  for (int i = 0; i < 32; i += 8)
    t[ty + i][tx] = vb[inbase + (size_t)(ty + i) * DIMSZ + tx];   // t[n][d]
  __syncthreads();
  const size_t outbase = ((size_t)bh * DHEAD + dt * 32) * NSEQ + nt * 32;
#pragma unroll
  for (int i = 0; i < 32; i += 8)
    vt[outbase + (size_t)(ty + i) * NSEQ + tx] = t[tx][ty + i];   // out[d][n]
}

// ---------------- bf16 MFMA NT-GEMM: C[M,N] = A[M,K] * B[N,K]^T ----------------
// R6 core: 128x128 tile, BK=32, 4 waves (2x2), 3-buffer ring, depth-2 prefetch,
// counted vmcnt(4), T2 swizzle (linear gload_lds dest, pre-swizzled source).
// z-batched: B strides by N*K per z; A strides by M*K if A_PER_Z; C selected
// from {C0,C1,C2}. WRITE_SSQ: row sum-of-squares of f32 acc -> atomicAdd(ssq).
template <int OUT_BF16, int WRITE_SSQ, int A_PER_Z>
__global__ __launch_bounds__(256) void gemm_nt_k(
    const ushort* __restrict__ A, const ushort* __restrict__ B,
    void* __restrict__ C0, void* __restrict__ C1, void* __restrict__ C2,
    float* __restrict__ ssq, int M, int N, int K) {
  __shared__ ushort As[3][128 * 32];
  __shared__ ushort Bs[3][128 * 32];
  const int z = blockIdx.z;
  const ushort* Az = A + (A_PER_Z ? (size_t)z * M * K : 0);
  const ushort* Bz = B + (size_t)z * N * K;
  void* Cout = (z == 0) ? C0 : (z == 1) ? C1 : C2;
  float* sz = WRITE_SSQ ? (ssq + (size_t)z * M) : nullptr;
  const int tid = threadIdx.x;
  const int lane = tid & 63;
  const int wid = tid >> 6;
  const int i0 = blockIdx.x * 128;
  const int n0 = blockIdx.y * 128;
  const int wr = (wid >> 1) * 64;
  const int wc = (wid & 1) * 64;
  f32x4 acc[4][4];
#pragma unroll
  for (int m = 0; m < 4; ++m)
#pragma unroll
    for (int n = 0; n < 4; ++n) acc[m][n] = (f32x4){0.f, 0.f, 0.f, 0.f};
  const int fr = lane & 15;
  const int g = lane >> 4;                       // quad-col 0..3
  const int kg = (g ^ ((fr >> 1) & 3)) * 8;      // swizzled read quad (shorts)
  const int srow = wid * 32 + (lane >> 2);
  const int skc = ((lane & 3) ^ ((lane >> 3) & 3)) * 8;
  const ushort* Ag = Az + (size_t)(i0 + srow) * K + skc;
  const ushort* Bg = Bz + (size_t)(n0 + srow) * K + skc;
  const int wb = wid * 1024;     // wave-uniform LDS base (shorts)

#define STAGE_TILE(tt, bb)                                      \
  do {                                                          \
    gl_lds16(Ag + (tt) * 32, &As[bb][wb]);                      \
    gl_lds16(Ag + (size_t)16 * K + (tt) * 32, &As[bb][wb + 512]); \
    gl_lds16(Bg + (tt) * 32, &Bs[bb][wb]);                      \
    gl_lds16(Bg + (size_t)16 * K + (tt) * 32, &Bs[bb][wb + 512]); \
  } while (0)

  const int nt = K >> 5;
  STAGE_TILE(0, 0);
  STAGE_TILE(1, 1);
  asm volatile("s_waitcnt vmcnt(4)" ::: "memory");
  __builtin_amdgcn_s_barrier();

  int cur = 0;
  for (int t = 0; t < nt; ++t) {
    if (t + 2 < nt) {
      const int nb = (cur >= 1) ? cur - 1 : cur + 2;   // (cur+2) mod 3
      STAGE_TILE(t + 2, nb);
    }
    bf16x8 af[4], bfr[4];
#pragma unroll
    for (int m = 0; m < 4; ++m)
      af[m] = *(const bf16x8*)&As[cur][(wr + m * 16 + fr) * 32 + kg];
#pragma unroll
    for (int n = 0; n < 4; ++n)
      bfr[n] = *(const bf16x8*)&Bs[cur][(wc + n * 16 + fr) * 32 + kg];
#pragma unroll
    for (int m = 0; m < 4; ++m)
#pragma unroll
      for (int n = 0; n < 4; ++n)
        acc[m][n] = __builtin_amdgcn_mfma_f32_16x16x32_bf16(af[m], bfr[n], acc[m][n], 0, 0, 0);
    if (t + 2 < nt)
      asm volatile("s_waitcnt vmcnt(4)" ::: "memory");  // t+1 done, t+2 in flight
    else
      asm volatile("s_waitcnt vmcnt(0)" ::: "memory");  // tail drain
    __builtin_amdgcn_s_barrier();
    cur = (cur == 2) ? 0 : cur + 1;
  }
#undef STAGE_TILE

  const int rq = lane >> 4;
#pragma unroll
  for (int m = 0; m < 4; ++m) {
#pragma unroll
    for (int n = 0; n < 4; ++n) {
#pragma unroll
      for (int rr = 0; rr < 4; ++rr) {
        const int row = i0 + wr + m * 16 + rq * 4 + rr;
        const int col = n0 + wc + n * 16 + fr;
        if (OUT_BF16)
          ((ushort*)Cout)[(size_t)row * N + col] = f2bf(acc[m][n][rr]);
        else
          ((float*)Cout)[(size_t)row * N + col] = acc[m][n][rr];
      }
    }
  }
  if (WRITE_SSQ) {
#pragma unroll
    for (int m = 0; m < 4; ++m) {
#pragma unroll
      for (int rr = 0; rr < 4; ++rr) {
        float s2 = acc[m][0][rr] * acc[m][0][rr] + acc[m][1][rr] * acc[m][1][rr] +
                   acc[m][2][rr] * acc[m][2][rr] + acc[m][3][rr] * acc[m][3][rr];
#pragma unroll
        for (int o = 1; o < 16; o <<= 1) s2 += __shfl_xor(s2, o);
        if (fr == 0) atomicAdd(&sz[i0 + wr + m * 16 + rq * 4 + rr], s2);
      }
    }
  }
}

// ---------------- MFMA bf16 flash attention (swapped-operand) ----------------
// R14: 64 q-rows per wave (was 32) -> per-KV-tile fixed overhead (staging
// ds_writes, 2 barriers, av/ones PV reads, K/V fetch) amortizes over 2x MFMA
// work. Grid (64,8) = 512 blocks = exactly 2/CU in ONE scheduling round.
// Per-m-half pipeline retained (S liveness 16 regs); m = 0..3. No min-waves
// bound (R7/R13: forcing below natural demand spills). Sentinel: WRITE~16384.
__global__ __launch_bounds__(256) void flash_mfma_k(
    const ushort* __restrict__ Qm, const ushort* __restrict__ Km,
    const ushort* __restrict__ Vt, ushort* __restrict__ Om) {
  __shared__ ushort Ks[64 * 72];
  __shared__ ushort Vs[65 * 72];      // V^T tile: [d][kv]; row 64 = ones
  __shared__ ushort Ps[4][64 * 72];   // per-wave P tile [q=64][kv]
  const int tid = threadIdx.x;
  const int lane = tid & 63;
  const int wid = tid >> 6;
  const int bh = blockIdx.x;          // 0..63
  const int qb = blockIdx.y;          // 0..7
  const int bidx = bh >> 4;
  const int h = bh & 15;
  const size_t rowbase = (size_t)bidx * NSEQ;
  const int colbase = h * DHEAD;
  const int fr = lane & 15;           // A-row / B-col select; q = m*16+fr
  const int g = lane >> 4;
  const int kg = g * 8;
  const int q0 = qb * 256 + wid * 64;

  if (tid < 64) Vs[64 * 72 + tid] = 0x3F80;   // bf16 1.0 ones-row

  bf16x8 qf[4][2];
#pragma unroll
  for (int m = 0; m < 4; ++m)
#pragma unroll
    for (int ks = 0; ks < 2; ++ks)
      qf[m][ks] = *(const bf16x8*)(Qm + (rowbase + q0 + m * 16 + fr) * (size_t)DIMSZ +
                                   colbase + ks * 32 + kg);

  f32x4 oaccT[4][4];
  f32x4 lacc[4];
#pragma unroll
  for (int m = 0; m < 4; ++m) {
#pragma unroll
    for (int n = 0; n < 4; ++n) oaccT[m][n] = (f32x4){0.f, 0.f, 0.f, 0.f};
    lacc[m] = (f32x4){0.f, 0.f, 0.f, 0.f};
  }
  float m2[4] = {-1e30f, -1e30f, -1e30f, -1e30f};
  const float c1 = 0.125f * 1.44269504088896340736f;  // scale * log2(e)

  const ushort* Kg = Km + rowbase * DIMSZ + colbase;
  const ushort* Vg = Vt + (size_t)bh * DHEAD * NSEQ;
  const int sr = tid >> 3;
  const int c8 = (tid & 7) * 8;

  uint4 k0 = *(const uint4*)(Kg + (size_t)sr * DIMSZ + c8);
  uint4 k1 = *(const uint4*)(Kg + (size_t)(sr + 32) * DIMSZ + c8);
  uint4 v0 = *(const uint4*)(Vg + (size_t)sr * NSEQ + c8);
  uint4 v1 = *(const uint4*)(Vg + (size_t)(sr + 32) * NSEQ + c8);

  for (int kt = 0; kt < NSEQ / 64; ++kt) {
    __syncthreads();
    *(uint4*)&Ks[sr * 72 + c8] = k0;
    *(uint4*)&Ks[(sr + 32) * 72 + c8] = k1;
    *(uint4*)&Vs[sr * 72 + c8] = v0;
    *(uint4*)&Vs[(sr + 32) * 72 + c8] = v1;
    __syncthreads();
    if (kt + 1 < NSEQ / 64) {
      k0 = *(const uint4*)(Kg + (size_t)((kt + 1) * 64 + sr) * DIMSZ + c8);
      k1 = *(const uint4*)(Kg + (size_t)((kt + 1) * 64 + sr + 32) * DIMSZ + c8);
      v0 = *(const uint4*)(Vg + (size_t)sr * NSEQ + (kt + 1) * 64 + c8);
      v1 = *(const uint4*)(Vg + (size_t)(sr + 32) * NSEQ + (kt + 1) * 64 + c8);
    }

    // ---- per-m-quarter: QK -> softmax -> P-write (S liveness = 16 regs) ----
#pragma unroll
    for (int m = 0; m < 4; ++m) {
      f32x4 s[4];
#pragma unroll
      for (int n = 0; n < 4; ++n) s[n] = (f32x4){0.f, 0.f, 0.f, 0.f};
      __builtin_amdgcn_s_setprio(1);
#pragma unroll
      for (int ks = 0; ks < 2; ++ks) {
        bf16x8 ak[4];
#pragma unroll
        for (int n = 0; n < 4; ++n)
          ak[n] = *(const bf16x8*)&Ks[(n * 16 + fr) * 72 + ks * 32 + kg];
#pragma unroll
        for (int n = 0; n < 4; ++n)
          s[n] = __builtin_amdgcn_mfma_f32_16x16x32_bf16(ak[n], qf[m][ks], s[n], 0, 0, 0);
      }
      __builtin_amdgcn_s_setprio(0);

      const float a0 = fmaxf(fmaxf(s[0][0], s[0][1]), s[0][2]);
      const float a1 = fmaxf(fmaxf(s[0][3], s[1][0]), s[1][1]);
      const float a2 = fmaxf(fmaxf(s[1][2], s[1][3]), s[2][0]);
      const float a3 = fmaxf(fmaxf(s[2][1], s[2][2]), s[2][3]);
      const float a4 = fmaxf(fmaxf(s[3][0], s[3][1]), s[3][2]);
      const float b0 = fmaxf(fmaxf(a0, a1), a2);
      const float b1 = fmaxf(fmaxf(a3, a4), s[3][3]);
      float tm = fmaxf(b0, b1);
      tm = fmaxf(tm, __shfl_xor(tm, 16));
      tm = fmaxf(tm, __shfl_xor(tm, 32));
      const float tm2 = tm * c1;
      if (!__all(tm2 <= m2[m] + 8.0f)) {
        const float mn2 = fmaxf(m2[m], tm2);
        const float al = exp2f(m2[m] - mn2);
        m2[m] = mn2;
        lacc[m] *= al;
#pragma unroll
        for (int n = 0; n < 4; ++n) oaccT[m][n] *= al;
      }
      const float mref = m2[m];
#pragma unroll
      for (int n = 0; n < 4; ++n)
#pragma unroll
        for (int rr = 0; rr < 4; ++rr)
          s[n][rr] = exp2f(fmaf(s[n][rr], c1, -mref));

      ushort* pw = &Ps[wid][0];
#pragma unroll
      for (int n = 0; n < 4; ++n) {
        uint2 w;
        w.x = cvt_pk_bf16(s[n][0], s[n][1]);
        w.y = cvt_pk_bf16(s[n][2], s[n][3]);
        *(uint2*)&pw[(m * 16 + fr) * 72 + n * 16 + g * 4] = w;
      }
    }

    // ---- O^T += V^T P (+ ones-row -> lacc), all 4 m; av shared across m ----
    __builtin_amdgcn_s_setprio(1);
#pragma unroll
    for (int ks = 0; ks < 2; ++ks) {
      bf16x8 av[4], pb[4];
      const bf16x8 av1 = *(const bf16x8*)&Vs[64 * 72 + ks * 32 + kg];  // ones
#pragma unroll
      for (int nd = 0; nd < 4; ++nd)
        av[nd] = *(const bf16x8*)&Vs[(nd * 16 + fr) * 72 + ks * 32 + kg];
#pragma unroll
      for (int m = 0; m < 4; ++m)
        pb[m] = *(const bf16x8*)&Ps[wid][(m * 16 + fr) * 72 + ks * 32 + kg];
#pragma unroll
      for (int m = 0; m < 4; ++m) {
#pragma unroll
        for (int nd = 0; nd < 4; ++nd)
          oaccT[m][nd] = __builtin_amdgcn_mfma_f32_16x16x32_bf16(av[nd], pb[m], oaccT[m][nd], 0, 0, 0);
        lacc[m] = __builtin_amdgcn_mfma_f32_16x16x32_bf16(av1, pb[m], lacc[m], 0, 0, 0);
      }
    }
    __builtin_amdgcn_s_setprio(0);
  }

#pragma unroll
  for (int m = 0; m < 4; ++m) {
    const float invl = 1.0f / lacc[m][0];
    const size_t row = rowbase + q0 + m * 16 + fr;
#pragma unroll
    for (int nd = 0; nd < 4; ++nd) {
      uint2 w;
      w.x = cvt_pk_bf16(oaccT[m][nd][0] * invl, oaccT[m][nd][1] * invl);
      w.y = cvt_pk_bf16(oaccT[m][nd][2] * invl, oaccT[m][nd][3] * invl);
      *(uint2*)(Om + row * DIMSZ + colbase + nd * 16 + g * 4) = w;
    }
  }
}

extern "C" void kernel_launch(void* const* d_in, const int* in_sizes, int n_in,
                              void* d_out, int out_size, void* d_ws, size_t ws_size,
                              hipStream_t stream) {
  (void)in_sizes; (void)n_in; (void)out_size; (void)ws_size;
  const float* x     = (const float*)d_in[0];
  const float* ln_g  = (const float*)d_in[1];
  const float* ln_b  = (const float*)d_in[2];
  const float* q_key = (const float*)d_in[3];
  const float* q_val = (const float*)d_in[4];
  const float* k_key = (const float*)d_in[5];
  const float* k_val = (const float*)d_in[6];
  const float* v_key = (const float*)d_in[7];
  const float* v_val = (const float*)d_in[8];
  const float* o_key = (const float*)d_in[9];
  const float* o_val = (const float*)d_in[10];
  float* out = (float*)d_out;

  char* ws = (char*)d_ws;
  const size_t MB = 1024 * 1024;
  ushort* xn    = (ushort*)(ws + 0 * MB);    // 16MB: x_norm bf16 [8192][1024]
  ushort* wkey  = (ushort*)(ws + 16 * MB);   // 8MB: 4x key bf16 [1024][1024]
  ushort* wvalT = (ushort*)(ws + 24 * MB);   // 8MB: 4x val^T bf16 [1024][1024]
  ushort* bufA  = (ushort*)(ws + 32 * MB);   // 16MB: q (stage2 out)
  ushort* bufB  = (ushort*)(ws + 48 * MB);   // 16MB: sim_q/gelu_q, later aout
  ushort* bufC  = (ushort*)(ws + 64 * MB);   // 16MB: sim_k/gelu_k, later sim_o
  ushort* bufD  = (ushort*)(ws + 80 * MB);   // 16MB: sim_v/gelu_v, later vt
  ushort* bufE  = (ushort*)(ws + 96 * MB);   // 16MB: k (stage2 out)
  // bufB/C/D are contiguous: z-stride = 8M shorts for batched sim/gelu.
  ushort* vscr  = (ushort*)d_out;            // 16MB of d_out: v (stage2 out)
  float*  ssqb  = (float*)((char*)d_out + 24 * MB);  // 4x[8192] f32 row-ssq

  const int NW = DIMSZ * DIMSZ;

  hipMemsetAsync(ssqb, 0, 4 * BN_TOT * sizeof(float), stream);
  layernorm_k<<<BN_TOT, 256, 0, stream>>>(x, ln_g, ln_b, xn);
  cvt4_k<<<dim3(1024, 1, 4), 256, 0, stream>>>(q_key, k_key, v_key, o_key, wkey);
  transpose_cvt4_k<<<dim3(32, 32, 4), 256, 0, stream>>>(q_val, k_val, v_val, o_val, wvalT);

  dim3 gg3(BN_TOT / 128, DIMSZ / 128, 3);
  dim3 gg1(BN_TOT / 128, DIMSZ / 128, 1);
  // stage1 qkv: sim_z = xn * key_z^T (bf16) + row ssq
  gemm_nt_k<1, 1, 0><<<gg3, 256, 0, stream>>>(
      xn, wkey, bufB, bufC, bufD, ssqb, BN_TOT, DIMSZ, DIMSZ);
  // normalize+gelu in place on sim_q/k/v
  normgelu_bf_k<<<dim3(BN_TOT, 3), 256, 0, stream>>>(bufB, ssqb);
  // stage2 qkv: out_z = gelu_z * valT_z^T -> q:bufA, k:bufE, v:d_out scratch
  gemm_nt_k<1, 0, 1><<<gg3, 256, 0, stream>>>(
      bufB, wvalT, bufA, bufE, vscr, nullptr, BN_TOT, DIMSZ, DIMSZ);

  transpose_v_k<<<dim3(64, 64, 2), 256, 0, stream>>>(vscr, bufD);
  flash_mfma_k<<<dim3(64, 8), 256, 0, stream>>>(bufA, bufE, bufD, bufB);

  // o-projection: sim_o = aout * o_key^T (bf16) + ssq slot 3
  gemm_nt_k<1, 1, 0><<<gg1, 256, 0, stream>>>(
      bufB, wkey + 3 * (size_t)NW, bufC, bufC, bufC, ssqb + 3 * BN_TOT,
      BN_TOT, DIMSZ, DIMSZ);
  normgelu_bf_k<<<dim3(BN_TOT, 1), 256, 0, stream>>>(bufC, ssqb + 3 * BN_TOT);
  // final: out = gelu_o * o_valT^T (f32) -> d_out
  gemm_nt_k<0, 0, 0><<<gg1, 256, 0, stream>>>(
      bufC, wvalT + 3 * (size_t)NW, out, out, out, nullptr, BN_TOT, DIMSZ, DIMSZ);
}

// Round 15
// 385.469 us; speedup vs baseline: 1.2071x; 1.2071x over previous
//
#include <hip/hip_runtime.h>
#include <hip/hip_bf16.h>
#include <stdint.h>

#define DIMSZ 1024
#define BN_TOT 8192   // B*N
#define NSEQ 2048
#define NHEADS 16
#define DHEAD 64

typedef __attribute__((ext_vector_type(8))) __bf16 bf16x8;
typedef __attribute__((ext_vector_type(4))) float f32x4;

__device__ __forceinline__ float bf2f(ushort u) {
  return __uint_as_float(((uint32_t)u) << 16);
}
__device__ __forceinline__ ushort f2bf(float f) {
  uint32_t u = __float_as_uint(f);
  u += 0x7FFFu + ((u >> 16) & 1u);   // round-to-nearest-even
  return (ushort)(u >> 16);
}
// pack two f32 -> two bf16 in one u32 (RNE), lo = first operand
__device__ __forceinline__ uint32_t cvt_pk_bf16(float lo, float hi) {
  uint32_t r;
  asm("v_cvt_pk_bf16_f32 %0, %1, %2" : "=v"(r) : "v"(lo), "v"(hi));
  return r;
}
// async global -> LDS, 16B per lane. LDS dest must be wave-uniform base.
__device__ __forceinline__ void gl_lds16(const ushort* g, ushort* l) {
  __builtin_amdgcn_global_load_lds(
      (const __attribute__((address_space(1))) void*)g,
      (__attribute__((address_space(3))) void*)l, 16, 0, 0);
}

// ---------------- LayerNorm: x[8192][1024] f32 -> xn bf16 ----------------
__global__ __launch_bounds__(256) void layernorm_k(
    const float* __restrict__ x, const float* __restrict__ gamma,
    const float* __restrict__ beta, ushort* __restrict__ xn) {
  const int row = blockIdx.x;
  const int tid = threadIdx.x;
  const float* xr = x + (size_t)row * DIMSZ;
  float4 v = *(const float4*)(xr + tid * 4);
  float s = v.x + v.y + v.z + v.w;
  float ss = v.x * v.x + v.y * v.y + v.z * v.z + v.w * v.w;
#pragma unroll
  for (int o = 1; o < 64; o <<= 1) { s += __shfl_xor(s, o); ss += __shfl_xor(ss, o); }
  __shared__ float red[2][4];
  const int wid = tid >> 6;
  if ((tid & 63) == 0) { red[0][wid] = s; red[1][wid] = ss; }
  __syncthreads();
  s = red[0][0] + red[0][1] + red[0][2] + red[0][3];
  ss = red[1][0] + red[1][1] + red[1][2] + red[1][3];
  const float mu = s * (1.0f / DIMSZ);
  const float var = ss * (1.0f / DIMSZ) - mu * mu;
  const float rstd = rsqrtf(var + 1e-5f);
  float4 g = *(const float4*)(gamma + tid * 4);
  float4 bb = *(const float4*)(beta + tid * 4);
  ushort4 o4;
  o4.x = f2bf((v.x - mu) * rstd * g.x + bb.x);
  o4.y = f2bf((v.y - mu) * rstd * g.y + bb.y);
  o4.z = f2bf((v.z - mu) * rstd * g.z + bb.z);
  o4.w = f2bf((v.w - mu) * rstd * g.w + bb.w);
  *(ushort4*)(xn + (size_t)row * DIMSZ + tid * 4) = o4;
}

// -- in-place row L2-normalize + exact GELU on bf16 buffer, ssq precomputed --
__global__ __launch_bounds__(256) void normgelu_bf_k(
    ushort* __restrict__ buf, const float* __restrict__ ssq) {
  const size_t row = (size_t)blockIdx.y * BN_TOT + blockIdx.x;
  ushort* p = buf + row * DIMSZ + threadIdx.x * 4;
  const float inv = 1.0f / fmaxf(sqrtf(ssq[row]), 1e-12f);
  ushort4 v = *(const ushort4*)p;
  ushort4 o4;
  float x0;
  x0 = bf2f(v.x) * inv; o4.x = f2bf(0.5f * x0 * (1.0f + erff(x0 * 0.70710678118654752f)));
  x0 = bf2f(v.y) * inv; o4.y = f2bf(0.5f * x0 * (1.0f + erff(x0 * 0.70710678118654752f)));
  x0 = bf2f(v.z) * inv; o4.z = f2bf(0.5f * x0 * (1.0f + erff(x0 * 0.70710678118654752f)));
  x0 = bf2f(v.w) * inv; o4.w = f2bf(0.5f * x0 * (1.0f + erff(x0 * 0.70710678118654752f)));
  *(ushort4*)p = o4;
}

// ----------- f32 -> bf16 copy, 4 weight matrices batched on z -----------
__global__ void cvt4_k(const float* __restrict__ s0, const float* __restrict__ s1,
                       const float* __restrict__ s2, const float* __restrict__ s3,
                       ushort* __restrict__ out) {
  const int z = blockIdx.z;
  const float* in = (z == 0) ? s0 : (z == 1) ? s1 : (z == 2) ? s2 : s3;
  const int i = (blockIdx.x * 256 + threadIdx.x) * 4;
  float4 v = *(const float4*)(in + i);
  ushort4 o;
  o.x = f2bf(v.x); o.y = f2bf(v.y); o.z = f2bf(v.z); o.w = f2bf(v.w);
  *(ushort4*)(out + (size_t)z * DIMSZ * DIMSZ + i) = o;
}

// -- transpose+convert val [P][E] f32 -> valT [E][P] bf16, 4 matrices on z --
__global__ __launch_bounds__(256) void transpose_cvt4_k(
    const float* __restrict__ s0, const float* __restrict__ s1,
    const float* __restrict__ s2, const float* __restrict__ s3,
    ushort* __restrict__ out) {
  __shared__ float t[32][33];
  const int z = blockIdx.z;
  const float* in = (z == 0) ? s0 : (z == 1) ? s1 : (z == 2) ? s2 : s3;
  ushort* dst = out + (size_t)z * DIMSZ * DIMSZ;
  const int tx = threadIdx.x & 31;
  const int ty = threadIdx.x >> 5;  // 0..7
  const int bx = blockIdx.x * 32;   // col block of in (E)
  const int by = blockIdx.y * 32;   // row block of in (P)
#pragma unroll
  for (int i = 0; i < 32; i += 8)
    t[ty + i][tx] = in[(size_t)(by + ty + i) * DIMSZ + bx + tx];
  __syncthreads();
#pragma unroll
  for (int i = 0; i < 32; i += 8)
    dst[(size_t)(bx + ty + i) * DIMSZ + by + tx] = f2bf(t[tx][ty + i]);
}

// ---- V transpose (bf16): vb[8192][1024] -> vt[64 bh][64 d][2048 n] ----
__global__ __launch_bounds__(256) void transpose_v_k(
    const ushort* __restrict__ vb, ushort* __restrict__ vt) {
  __shared__ ushort t[32][33];
  const int bh = blockIdx.x;        // 0..63
  const int nt = blockIdx.y;        // 0..63 (n tile)
  const int dt = blockIdx.z;        // 0..1  (d tile)
  const int b = bh >> 4, h = bh & 15;
  const int tx = threadIdx.x & 31;
  const int ty = threadIdx.x >> 5;  // 0..7
  const size_t inbase = ((size_t)b * NSEQ + nt * 32) * DIMSZ + h * DHEAD + dt * 32;
#pragma unroll
  for (int i = 0; i < 32; i += 8)
    t[ty + i][tx] = vb[inbase + (size_t)(ty + i) * DIMSZ + tx];   // t[n][d]
  __syncthreads();
  const size_t outbase = ((size_t)bh * DHEAD + dt * 32) * NSEQ + nt * 32;
#pragma unroll
  for (int i = 0; i < 32; i += 8)
    vt[outbase + (size_t)(ty + i) * NSEQ + tx] = t[tx][ty + i];   // out[d][n]
}

// ---------------- bf16 MFMA NT-GEMM: C[M,N] = A[M,K] * B[N,K]^T ----------------
// R6 core: 128x128 tile, BK=32, 4 waves (2x2), 3-buffer ring, depth-2 prefetch,
// counted vmcnt(4), T2 swizzle (linear gload_lds dest, pre-swizzled source).
// z-batched: B strides by N*K per z; A strides by M*K if A_PER_Z; C selected
// from {C0,C1,C2}. WRITE_SSQ: row sum-of-squares of f32 acc -> atomicAdd(ssq).
template <int OUT_BF16, int WRITE_SSQ, int A_PER_Z>
__global__ __launch_bounds__(256) void gemm_nt_k(
    const ushort* __restrict__ A, const ushort* __restrict__ B,
    void* __restrict__ C0, void* __restrict__ C1, void* __restrict__ C2,
    float* __restrict__ ssq, int M, int N, int K) {
  __shared__ ushort As[3][128 * 32];
  __shared__ ushort Bs[3][128 * 32];
  const int z = blockIdx.z;
  const ushort* Az = A + (A_PER_Z ? (size_t)z * M * K : 0);
  const ushort* Bz = B + (size_t)z * N * K;
  void* Cout = (z == 0) ? C0 : (z == 1) ? C1 : C2;
  float* sz = WRITE_SSQ ? (ssq + (size_t)z * M) : nullptr;
  const int tid = threadIdx.x;
  const int lane = tid & 63;
  const int wid = tid >> 6;
  const int i0 = blockIdx.x * 128;
  const int n0 = blockIdx.y * 128;
  const int wr = (wid >> 1) * 64;
  const int wc = (wid & 1) * 64;
  f32x4 acc[4][4];
#pragma unroll
  for (int m = 0; m < 4; ++m)
#pragma unroll
    for (int n = 0; n < 4; ++n) acc[m][n] = (f32x4){0.f, 0.f, 0.f, 0.f};
  const int fr = lane & 15;
  const int g = lane >> 4;                       // quad-col 0..3
  const int kg = (g ^ ((fr >> 1) & 3)) * 8;      // swizzled read quad (shorts)
  const int srow = wid * 32 + (lane >> 2);
  const int skc = ((lane & 3) ^ ((lane >> 3) & 3)) * 8;
  const ushort* Ag = Az + (size_t)(i0 + srow) * K + skc;
  const ushort* Bg = Bz + (size_t)(n0 + srow) * K + skc;
  const int wb = wid * 1024;     // wave-uniform LDS base (shorts)

#define STAGE_TILE(tt, bb)                                      \
  do {                                                          \
    gl_lds16(Ag + (tt) * 32, &As[bb][wb]);                      \
    gl_lds16(Ag + (size_t)16 * K + (tt) * 32, &As[bb][wb + 512]); \
    gl_lds16(Bg + (tt) * 32, &Bs[bb][wb]);                      \
    gl_lds16(Bg + (size_t)16 * K + (tt) * 32, &Bs[bb][wb + 512]); \
  } while (0)

  const int nt = K >> 5;
  STAGE_TILE(0, 0);
  STAGE_TILE(1, 1);
  asm volatile("s_waitcnt vmcnt(4)" ::: "memory");
  __builtin_amdgcn_s_barrier();

  int cur = 0;
  for (int t = 0; t < nt; ++t) {
    if (t + 2 < nt) {
      const int nb = (cur >= 1) ? cur - 1 : cur + 2;   // (cur+2) mod 3
      STAGE_TILE(t + 2, nb);
    }
    bf16x8 af[4], bfr[4];
#pragma unroll
    for (int m = 0; m < 4; ++m)
      af[m] = *(const bf16x8*)&As[cur][(wr + m * 16 + fr) * 32 + kg];
#pragma unroll
    for (int n = 0; n < 4; ++n)
      bfr[n] = *(const bf16x8*)&Bs[cur][(wc + n * 16 + fr) * 32 + kg];
#pragma unroll
    for (int m = 0; m < 4; ++m)
#pragma unroll
      for (int n = 0; n < 4; ++n)
        acc[m][n] = __builtin_amdgcn_mfma_f32_16x16x32_bf16(af[m], bfr[n], acc[m][n], 0, 0, 0);
    if (t + 2 < nt)
      asm volatile("s_waitcnt vmcnt(4)" ::: "memory");  // t+1 done, t+2 in flight
    else
      asm volatile("s_waitcnt vmcnt(0)" ::: "memory");  // tail drain
    __builtin_amdgcn_s_barrier();
    cur = (cur == 2) ? 0 : cur + 1;
  }
#undef STAGE_TILE

  const int rq = lane >> 4;
#pragma unroll
  for (int m = 0; m < 4; ++m) {
#pragma unroll
    for (int n = 0; n < 4; ++n) {
#pragma unroll
      for (int rr = 0; rr < 4; ++rr) {
        const int row = i0 + wr + m * 16 + rq * 4 + rr;
        const int col = n0 + wc + n * 16 + fr;
        if (OUT_BF16)
          ((ushort*)Cout)[(size_t)row * N + col] = f2bf(acc[m][n][rr]);
        else
          ((float*)Cout)[(size_t)row * N + col] = acc[m][n][rr];
      }
    }
  }
  if (WRITE_SSQ) {
#pragma unroll
    for (int m = 0; m < 4; ++m) {
#pragma unroll
      for (int rr = 0; rr < 4; ++rr) {
        float s2 = acc[m][0][rr] * acc[m][0][rr] + acc[m][1][rr] * acc[m][1][rr] +
                   acc[m][2][rr] * acc[m][2][rr] + acc[m][3][rr] * acc[m][3][rr];
#pragma unroll
        for (int o = 1; o < 16; o <<= 1) s2 += __shfl_xor(s2, o);
        if (fr == 0) atomicAdd(&sz[i0 + wr + m * 16 + rq * 4 + rr], s2);
      }
    }
  }
}

// ---------------- MFMA bf16 flash attention (swapped-operand) ----------------
// R12 configuration restored -- verified best of six variants:
//   R8  112 VGPR / 20% occ / 164 us      R10/R12  80 VGPR / 26% occ / 150.7 us
//   R11 dbuf 104 VGPR / 20% / 155 us     R13 64+spill / 37% / 152 us
//   R14 64q/wave 136 VGPR / 11.5% / 235 us
// Per-m-half pipeline (S liveness 16 regs); (256,3) bound = no spill;
// 2-barrier single-buffer K/V loop. Sentinel: WRITE_SIZE == 16384 KB.
__global__ __launch_bounds__(256, 3) void flash_mfma_k(
    const ushort* __restrict__ Qm, const ushort* __restrict__ Km,
    const ushort* __restrict__ Vt, ushort* __restrict__ Om) {
  __shared__ ushort Ks[64 * 72];
  __shared__ ushort Vs[65 * 72];      // V^T tile: [d][kv]; row 64 = ones
  __shared__ ushort Ps[4][32 * 72];   // per-wave P tile [q][kv]
  const int tid = threadIdx.x;
  const int lane = tid & 63;
  const int wid = tid >> 6;
  const int bh = blockIdx.x;          // 0..63
  const int qb = blockIdx.y;          // 0..15
  const int bidx = bh >> 4;
  const int h = bh & 15;
  const size_t rowbase = (size_t)bidx * NSEQ;
  const int colbase = h * DHEAD;
  const int fr = lane & 15;           // A-row / B-col select; q = m*16+fr
  const int g = lane >> 4;
  const int kg = g * 8;
  const int q0 = qb * 128 + wid * 32;

  if (tid < 64) Vs[64 * 72 + tid] = 0x3F80;   // bf16 1.0 ones-row

  bf16x8 qf[2][2];
#pragma unroll
  for (int m = 0; m < 2; ++m)
#pragma unroll
    for (int ks = 0; ks < 2; ++ks)
      qf[m][ks] = *(const bf16x8*)(Qm + (rowbase + q0 + m * 16 + fr) * (size_t)DIMSZ +
                                   colbase + ks * 32 + kg);

  f32x4 oaccT[2][4];
  f32x4 lacc[2];
#pragma unroll
  for (int m = 0; m < 2; ++m) {
#pragma unroll
    for (int n = 0; n < 4; ++n) oaccT[m][n] = (f32x4){0.f, 0.f, 0.f, 0.f};
    lacc[m] = (f32x4){0.f, 0.f, 0.f, 0.f};
  }
  float m2[2] = {-1e30f, -1e30f};
  const float c1 = 0.125f * 1.44269504088896340736f;  // scale * log2(e)

  const ushort* Kg = Km + rowbase * DIMSZ + colbase;
  const ushort* Vg = Vt + (size_t)bh * DHEAD * NSEQ;
  const int sr = tid >> 3;
  const int c8 = (tid & 7) * 8;

  uint4 k0 = *(const uint4*)(Kg + (size_t)sr * DIMSZ + c8);
  uint4 k1 = *(const uint4*)(Kg + (size_t)(sr + 32) * DIMSZ + c8);
  uint4 v0 = *(const uint4*)(Vg + (size_t)sr * NSEQ + c8);
  uint4 v1 = *(const uint4*)(Vg + (size_t)(sr + 32) * NSEQ + c8);

  for (int kt = 0; kt < NSEQ / 64; ++kt) {
    __syncthreads();
    *(uint4*)&Ks[sr * 72 + c8] = k0;
    *(uint4*)&Ks[(sr + 32) * 72 + c8] = k1;
    *(uint4*)&Vs[sr * 72 + c8] = v0;
    *(uint4*)&Vs[(sr + 32) * 72 + c8] = v1;
    __syncthreads();
    if (kt + 1 < NSEQ / 64) {
      k0 = *(const uint4*)(Kg + (size_t)((kt + 1) * 64 + sr) * DIMSZ + c8);
      k1 = *(const uint4*)(Kg + (size_t)((kt + 1) * 64 + sr + 32) * DIMSZ + c8);
      v0 = *(const uint4*)(Vg + (size_t)sr * NSEQ + (kt + 1) * 64 + c8);
      v1 = *(const uint4*)(Vg + (size_t)(sr + 32) * NSEQ + (kt + 1) * 64 + c8);
    }

    // ---- per-m-half: QK -> softmax -> P-write (S liveness = 16 regs) ----
#pragma unroll
    for (int m = 0; m < 2; ++m) {
      f32x4 s[4];
#pragma unroll
      for (int n = 0; n < 4; ++n) s[n] = (f32x4){0.f, 0.f, 0.f, 0.f};
      __builtin_amdgcn_s_setprio(1);
#pragma unroll
      for (int ks = 0; ks < 2; ++ks) {
        bf16x8 ak[4];
#pragma unroll
        for (int n = 0; n < 4; ++n)
          ak[n] = *(const bf16x8*)&Ks[(n * 16 + fr) * 72 + ks * 32 + kg];
#pragma unroll
        for (int n = 0; n < 4; ++n)
          s[n] = __builtin_amdgcn_mfma_f32_16x16x32_bf16(ak[n], qf[m][ks], s[n], 0, 0, 0);
      }
      __builtin_amdgcn_s_setprio(0);

      const float a0 = fmaxf(fmaxf(s[0][0], s[0][1]), s[0][2]);
      const float a1 = fmaxf(fmaxf(s[0][3], s[1][0]), s[1][1]);
      const float a2 = fmaxf(fmaxf(s[1][2], s[1][3]), s[2][0]);
      const float a3 = fmaxf(fmaxf(s[2][1], s[2][2]), s[2][3]);
      const float a4 = fmaxf(fmaxf(s[3][0], s[3][1]), s[3][2]);
      const float b0 = fmaxf(fmaxf(a0, a1), a2);
      const float b1 = fmaxf(fmaxf(a3, a4), s[3][3]);
      float tm = fmaxf(b0, b1);
      tm = fmaxf(tm, __shfl_xor(tm, 16));
      tm = fmaxf(tm, __shfl_xor(tm, 32));
      const float tm2 = tm * c1;
      if (!__all(tm2 <= m2[m] + 8.0f)) {
        const float mn2 = fmaxf(m2[m], tm2);
        const float al = exp2f(m2[m] - mn2);
        m2[m] = mn2;
        lacc[m] *= al;
#pragma unroll
        for (int n = 0; n < 4; ++n) oaccT[m][n] *= al;
      }
      const float mref = m2[m];
#pragma unroll
      for (int n = 0; n < 4; ++n)
#pragma unroll
        for (int rr = 0; rr < 4; ++rr)
          s[n][rr] = exp2f(fmaf(s[n][rr], c1, -mref));

      ushort* pw = &Ps[wid][0];
#pragma unroll
      for (int n = 0; n < 4; ++n) {
        uint2 w;
        w.x = cvt_pk_bf16(s[n][0], s[n][1]);
        w.y = cvt_pk_bf16(s[n][2], s[n][3]);
        *(uint2*)&pw[(m * 16 + fr) * 72 + n * 16 + g * 4] = w;
      }
    }

    // ---- O^T += V^T P (+ ones-row -> lacc), both m ----
    __builtin_amdgcn_s_setprio(1);
#pragma unroll
    for (int ks = 0; ks < 2; ++ks) {
      bf16x8 av[4], pb[2];
      const bf16x8 av1 = *(const bf16x8*)&Vs[64 * 72 + ks * 32 + kg];  // ones
#pragma unroll
      for (int nd = 0; nd < 4; ++nd)
        av[nd] = *(const bf16x8*)&Vs[(nd * 16 + fr) * 72 + ks * 32 + kg];
#pragma unroll
      for (int m = 0; m < 2; ++m)
        pb[m] = *(const bf16x8*)&Ps[wid][(m * 16 + fr) * 72 + ks * 32 + kg];
#pragma unroll
      for (int m = 0; m < 2; ++m) {
#pragma unroll
        for (int nd = 0; nd < 4; ++nd)
          oaccT[m][nd] = __builtin_amdgcn_mfma_f32_16x16x32_bf16(av[nd], pb[m], oaccT[m][nd], 0, 0, 0);
        lacc[m] = __builtin_amdgcn_mfma_f32_16x16x32_bf16(av1, pb[m], lacc[m], 0, 0, 0);
      }
    }
    __builtin_amdgcn_s_setprio(0);
  }

#pragma unroll
  for (int m = 0; m < 2; ++m) {
    const float invl = 1.0f / lacc[m][0];
    const size_t row = rowbase + q0 + m * 16 + fr;
#pragma unroll
    for (int nd = 0; nd < 4; ++nd) {
      uint2 w;
      w.x = cvt_pk_bf16(oaccT[m][nd][0] * invl, oaccT[m][nd][1] * invl);
      w.y = cvt_pk_bf16(oaccT[m][nd][2] * invl, oaccT[m][nd][3] * invl);
      *(uint2*)(Om + row * DIMSZ + colbase + nd * 16 + g * 4) = w;
    }
  }
}

extern "C" void kernel_launch(void* const* d_in, const int* in_sizes, int n_in,
                              void* d_out, int out_size, void* d_ws, size_t ws_size,
                              hipStream_t stream) {
  (void)in_sizes; (void)n_in; (void)out_size; (void)ws_size;
  const float* x     = (const float*)d_in[0];
  const float* ln_g  = (const float*)d_in[1];
  const float* ln_b  = (const float*)d_in[2];
  const float* q_key = (const float*)d_in[3];
  const float* q_val = (const float*)d_in[4];
  const float* k_key = (const float*)d_in[5];
  const float* k_val = (const float*)d_in[6];
  const float* v_key = (const float*)d_in[7];
  const float* v_val = (const float*)d_in[8];
  const float* o_key = (const float*)d_in[9];
  const float* o_val = (const float*)d_in[10];
  float* out = (float*)d_out;

  char* ws = (char*)d_ws;
  const size_t MB = 1024 * 1024;
  ushort* xn    = (ushort*)(ws + 0 * MB);    // 16MB: x_norm bf16 [8192][1024]
  ushort* wkey  = (ushort*)(ws + 16 * MB);   // 8MB: 4x key bf16 [1024][1024]
  ushort* wvalT = (ushort*)(ws + 24 * MB);   // 8MB: 4x val^T bf16 [1024][1024]
  ushort* bufA  = (ushort*)(ws + 32 * MB);   // 16MB: q (stage2 out)
  ushort* bufB  = (ushort*)(ws + 48 * MB);   // 16MB: sim_q/gelu_q, later aout
  ushort* bufC  = (ushort*)(ws + 64 * MB);   // 16MB: sim_k/gelu_k, later sim_o
  ushort* bufD  = (ushort*)(ws + 80 * MB);   // 16MB: sim_v/gelu_v, later vt
  ushort* bufE  = (ushort*)(ws + 96 * MB);   // 16MB: k (stage2 out)
  // bufB/C/D are contiguous: z-stride = 8M shorts for batched sim/gelu.
  ushort* vscr  = (ushort*)d_out;            // 16MB of d_out: v (stage2 out)
  float*  ssqb  = (float*)((char*)d_out + 24 * MB);  // 4x[8192] f32 row-ssq

  const int NW = DIMSZ * DIMSZ;

  hipMemsetAsync(ssqb, 0, 4 * BN_TOT * sizeof(float), stream);
  layernorm_k<<<BN_TOT, 256, 0, stream>>>(x, ln_g, ln_b, xn);
  cvt4_k<<<dim3(1024, 1, 4), 256, 0, stream>>>(q_key, k_key, v_key, o_key, wkey);
  transpose_cvt4_k<<<dim3(32, 32, 4), 256, 0, stream>>>(q_val, k_val, v_val, o_val, wvalT);

  dim3 gg3(BN_TOT / 128, DIMSZ / 128, 3);
  dim3 gg1(BN_TOT / 128, DIMSZ / 128, 1);
  // stage1 qkv: sim_z = xn * key_z^T (bf16) + row ssq
  gemm_nt_k<1, 1, 0><<<gg3, 256, 0, stream>>>(
      xn, wkey, bufB, bufC, bufD, ssqb, BN_TOT, DIMSZ, DIMSZ);
  // normalize+gelu in place on sim_q/k/v
  normgelu_bf_k<<<dim3(BN_TOT, 3), 256, 0, stream>>>(bufB, ssqb);
  // stage2 qkv: out_z = gelu_z * valT_z^T -> q:bufA, k:bufE, v:d_out scratch
  gemm_nt_k<1, 0, 1><<<gg3, 256, 0, stream>>>(
      bufB, wvalT, bufA, bufE, vscr, nullptr, BN_TOT, DIMSZ, DIMSZ);

  transpose_v_k<<<dim3(64, 64, 2), 256, 0, stream>>>(vscr, bufD);
  flash_mfma_k<<<dim3(64, 16), 256, 0, stream>>>(bufA, bufE, bufD, bufB);

  // o-projection: sim_o = aout * o_key^T (bf16) + ssq slot 3
  gemm_nt_k<1, 1, 0><<<gg1, 256, 0, stream>>>(
      bufB, wkey + 3 * (size_t)NW, bufC, bufC, bufC, ssqb + 3 * BN_TOT,
      BN_TOT, DIMSZ, DIMSZ);
  normgelu_bf_k<<<dim3(BN_TOT, 1), 256, 0, stream>>>(bufC, ssqb + 3 * BN_TOT);
  // final: out = gelu_o * o_valT^T (f32) -> d_out
  gemm_nt_k<0, 0, 0><<<gg1, 256, 0, stream>>>(
      bufC, wvalT + 3 * (size_t)NW, out, out, out, nullptr, BN_TOT, DIMSZ, DIMSZ);
}